// Round 20
// baseline (337.952 us; speedup 1.0000x reference)
//
#include <hip/hip_runtime.h>
#include <hip/hip_bf16.h>

#define N_NODES 20000
#define NH      8
#define NG      16      // node groups; 16*NG = 256 blocks (= 1 block/CU)
#define G2      1250    // nodes per group (16*1250 = 20000 exactly)
#define FEPS    1e-6f
#define XS_LD   264     // padded stride for [*][256] bf16 tiles (528B rows)
#define TL      72      // padded stride for [256][64]/[128][64] bf16 tiles (144B rows)
#define P3R     80      // pass-3 rows per block (250 * 80 = 20000 exactly)

typedef __attribute__((ext_vector_type(8))) short bf16x8;
typedef __attribute__((ext_vector_type(4))) float f32x4;
typedef unsigned short u16;

__device__ __forceinline__ float bf2f(u16 u) {
    union { unsigned int i; float f; } v; v.i = ((unsigned int)u) << 16; return v.f;
}
__device__ __forceinline__ u16 f2bf(float f) {
    union { float f; unsigned int i; } v; v.f = f;
    return (u16)((v.i + 0x7fffu + ((v.i >> 16) & 1u)) >> 16);
}
__device__ __forceinline__ int pk2(float a, float b) {
    return (int)f2bf(a) | ((int)f2bf(b) << 16);
}
__device__ __forceinline__ int4 cvt8(const float* __restrict__ s) {
    float4 a = *(const float4*)s;
    float4 b = *(const float4*)(s + 4);
    int4 w;
    w.x = pk2(a.x, a.y); w.y = pk2(a.z, a.w);
    w.z = pk2(b.x, b.y); w.w = pk2(b.z, b.w);
    return w;
}
// KT/VT chunk swizzle: logical column col of row `row` lives at physical
// column ((col>>3) ^ ((row>>2)&7))<<3 | (col&7). Bijective per row; applied
// identically at all KT/VT access sites -> bitwise-identical results.
__device__ __forceinline__ int swzc(int row, int col) {
    return ((((col >> 3) ^ ((row >> 2) & 7)) << 3) | (col & 7));
}

// ---------------- fused prologue A: z<3 -> convert Wq/Wk/Wv; z==3 -> Wsum ----------------
__global__ __launch_bounds__(256) void wprep_kernel(
    const float* __restrict__ Wq, const float* __restrict__ Wk, const float* __restrict__ Wv,
    u16* __restrict__ Wqb, u16* __restrict__ Wkb, u16* __restrict__ Wvb,
    float* __restrict__ Wsum)
{
    const int z = blockIdx.y;
    if (z < 3) {
        const float* s = (z == 0) ? Wq : (z == 1) ? Wk : Wv;
        u16* d = (z == 0) ? Wqb : (z == 1) ? Wkb : Wvb;
        int i = blockIdx.x * 256 + threadIdx.x;    // 131072 float4s exactly
        float4 v = reinterpret_cast<const float4*>(s)[i];
        ushort4 o;
        o.x = f2bf(v.x); o.y = f2bf(v.y); o.z = f2bf(v.z); o.w = f2bf(v.w);
        reinterpret_cast<ushort4*>(d)[i] = o;
    } else {
        if (blockIdx.x >= 256) return;
        int i = blockIdx.x * 256 + threadIdx.x;    // 65536 elements
        float s = 0.f;
#pragma unroll
        for (int h = 0; h < NH; ++h) s += Wv[(size_t)h * 65536 + i];
        Wsum[i] = s;
    }
}

// ---------------- fused prologue B: o<256 -> Wavg row; o==256 -> bavg ----------------
__global__ __launch_bounds__(256) void wfin_kernel(
    const float* __restrict__ Wsum, const float* __restrict__ vmap_w,
    const float* __restrict__ bv, const float* __restrict__ vmap_b,
    u16* __restrict__ Wavg, float* __restrict__ bavg)
{
    const int o = blockIdx.x, t = threadIdx.x;
    __shared__ float buf[256];
    if (o < 256) {
        buf[t] = vmap_w[(size_t)o * 256 + t];
        __syncthreads();
        float acc = 0.f;
#pragma unroll 4
        for (int e = 0; e < 256; ++e)
            acc += buf[e] * Wsum[(size_t)e * 256 + t];
        Wavg[(size_t)o * 256 + t] = f2bf(acc * 0.125f);
    } else {
        float s = 0.f;
        for (int h = 0; h < NH; ++h) s += bv[h * 256 + t];
        buf[t] = s * 0.125f;
        __syncthreads();
        float acc = vmap_b[t];
        for (int e = 0; e < 256; ++e) acc += vmap_w[(size_t)t * 256 + e] * buf[e];
        bavg[t] = acc;
    }
}

// ---------------- pass 2: K/V proj + phi + ktv partial (256 blocks, 512 thr) ----------------
// bid -> h = bid&7 (XCD pin), g = (bid>>3)%NG, dh = (bid>>3)/NG.
// = R12/R17/R19 (314.4us x3) + KT/VT chunk-XOR swizzle: the scalar u16 epilogue
// writes were 4-way bank-conflicted (row stride 144B -> 16-bank kgrp step); the
// swizzle makes them 2-way (free) while keeping all b128 read patterns ideal
// (verified by bank enumeration). Pure per-row bijection -> identical output.
__global__ __launch_bounds__(512, 2) void pass2_kernel(
    const float* __restrict__ srcf,
    const u16* __restrict__ Wkb, const float* __restrict__ bk,
    const u16* __restrict__ Wvb, const float* __restrict__ bv,
    const float* __restrict__ ns_ptr,
    u16* __restrict__ P,
    float* __restrict__ ksum)
{
    const int bid = blockIdx.x;
    const int h = bid & 7, gr = bid >> 3, g = gr % NG, dh = gr / NG;
    const int t = threadIdx.x;
    const int lane = t & 63, wid = t >> 6;      // 8 waves
    const int r16 = lane & 15, kgrp = lane >> 4;

    __shared__ char smem[75008];
    u16* Xs = (u16*)smem;                        // [64][XS_LD]  33792 B
    u16* VT = (u16*)smem;                        // [128][TL] 18432 B, OVERLAYS Xs
    u16* KT = (u16*)(smem + 33792);              // [256][TL]    36864 B
    float* red = (float*)(smem + 70656);         // 1024 f32
    float* scl = (float*)(smem + 74752);         // 64 f32

    const float inv_ns = 1.0f / fabsf(ns_ptr[0]);
    const u16* Wkh = Wkb + (size_t)h * 65536;
    const u16* Wvh = Wvb + (size_t)h * 65536;

    const int n0g = g * G2;
    const int rlim = min(G2, N_NODES - n0g);
    const int nt = (rlim + 63) >> 6;

    f32x4 kacc[2][8];
#pragma unroll
    for (int i = 0; i < 2; ++i)
#pragma unroll
        for (int j = 0; j < 8; ++j) kacc[i][j] = (f32x4){0.f, 0.f, 0.f, 0.f};
    float ksr = 0.f;

    for (int it = 0; it < nt; ++it) {
        const int ln0 = it * 64;
        __syncthreads();                                     // S0: prev iter VT reads done (overlay)
        // ---- stage X tile: fp32 -> bf16 in-register ----
#pragma unroll
        for (int p = 0; p < 4; ++p) {
            int id = p * 512 + t;
            int row = id >> 5, col = (id & 31) * 8;
            int4 w = {0, 0, 0, 0};
            if (ln0 + row < rlim)
                w = cvt8(srcf + ((size_t)(n0g + ln0 + row) * 256 + col));
            *(int4*)&Xs[row * XS_LD + col] = w;
        }
        __syncthreads();                                     // S1

        // ---- K-GEMM: C[m 256][n 64]; weights from L2 ----
        f32x4 acc2[2][4];
#pragma unroll
        for (int i = 0; i < 2; ++i)
#pragma unroll
            for (int j = 0; j < 4; ++j) acc2[i][j] = (f32x4){0.f, 0.f, 0.f, 0.f};
#pragma unroll
        for (int kc = 0; kc < 4; ++kc) {
#pragma unroll
            for (int kk = 0; kk < 2; ++kk) {
                bf16x8 a[2];
#pragma unroll
                for (int i = 0; i < 2; ++i)
                    a[i] = *(const bf16x8*)&Wkh[(size_t)(wid * 32 + i * 16 + r16) * 256 + kc * 64 + kk * 32 + kgrp * 8];
#pragma unroll
                for (int j = 0; j < 4; ++j) {
                    bf16x8 b = *(const bf16x8*)&Xs[(j * 16 + r16) * XS_LD + kc * 64 + kk * 32 + kgrp * 8];
#pragma unroll
                    for (int i = 0; i < 2; ++i)
                        acc2[i][j] = __builtin_amdgcn_mfma_f32_16x16x32_bf16(a[i], b, acc2[i][j], 0, 0, 0);
                }
            }
        }
        // epilogue -> KT (swizzled): (relu + eps) * inv_ns
#pragma unroll
        for (int i = 0; i < 2; ++i) {
#pragma unroll
            for (int j = 0; j < 4; ++j) {
                int n = j * 16 + r16;
#pragma unroll
                for (int r = 0; r < 4; ++r) {
                    int m = wid * 32 + i * 16 + kgrp * 4 + r;
                    float x = acc2[i][j][r] + bk[h * 256 + m];
                    x = (fmaxf(x, 0.f) + FEPS) * inv_ns;
                    KT[m * TL + swzc(m, n)] = f2bf(x);
                }
            }
        }
        __syncthreads();                                     // S2
        // ---- column reductions: per node c, s1=sum_m k'^2, s2=sum_m k'^4 ----
        {
            int c = t & 63, ch = t >> 6;
            float s1 = 0.f, s2 = 0.f;
#pragma unroll
            for (int i = 0; i < 32; ++i) {
                int row = ch * 32 + i;
                float x = bf2f(KT[row * TL + swzc(row, c)]);
                float q = x * x;
                s1 += q; s2 += q * q;
            }
            red[ch * 64 + c] = s1;
            red[512 + ch * 64 + c] = s2;
        }
        __syncthreads();                                     // S3
        if (t < 64) {
            float s1 = 0.f, s2 = 0.f;
#pragma unroll
            for (int ch = 0; ch < 8; ++ch) {
                s1 += red[ch * 64 + t];
                s2 += red[512 + ch * 64 + t];
            }
            scl[t] = (ln0 + t < rlim) ? sqrtf(s1) / sqrtf(s2) : 0.f;
        }
        __syncthreads();                                     // S4
        // ---- phi in place (row m = t>>1, n-half (t&1)*32) + ksum partial ----
        {
            const int m = t >> 1, q0 = (t & 1) * 32;
            float kp = 0.f;
#pragma unroll
            for (int j = 0; j < 4; ++j) {
                int col = swzc(m, q0 + j * 8);               // chunk-aligned
                bf16x8 v8 = *(const bf16x8*)&KT[m * TL + col];
                bf16x8 w8;
#pragma unroll
                for (int jj = 0; jj < 8; ++jj) {
                    float x = bf2f((u16)v8[jj]);
                    float ph = x * x * scl[q0 + j * 8 + jj];
                    u16 pb = f2bf(ph);
                    w8[jj] = (short)pb;
                    kp += bf2f(pb);
                }
                *(bf16x8*)&KT[m * TL + col] = w8;
            }
            ksr += kp;
        }
        // ---- V-GEMM (d-half): C[dl 128][n 64]; all results in regs before overlay ----
        f32x4 accv[4];
#pragma unroll
        for (int j = 0; j < 4; ++j) accv[j] = (f32x4){0.f, 0.f, 0.f, 0.f};
#pragma unroll
        for (int kc = 0; kc < 4; ++kc) {
#pragma unroll
            for (int kk = 0; kk < 2; ++kk) {
                bf16x8 a = *(const bf16x8*)&Wvh[(size_t)(dh * 128 + wid * 16 + r16) * 256 + kc * 64 + kk * 32 + kgrp * 8];
#pragma unroll
                for (int j = 0; j < 4; ++j) {
                    bf16x8 b = *(const bf16x8*)&Xs[(j * 16 + r16) * XS_LD + kc * 64 + kk * 32 + kgrp * 8];
                    accv[j] = __builtin_amdgcn_mfma_f32_16x16x32_bf16(a, b, accv[j], 0, 0, 0);
                }
            }
        }
        __syncthreads();                                     // S5: all Xs reads done; phi'd KT visible
        // ---- write VT over Xs region (swizzled) ----
#pragma unroll
        for (int j = 0; j < 4; ++j) {
            int n = j * 16 + r16;
#pragma unroll
            for (int r = 0; r < 4; ++r) {
                int dl = wid * 16 + kgrp * 4 + r;
                VT[dl * TL + swzc(dl, n)] = f2bf(accv[j][r] + bv[h * 256 + dh * 128 + dl]);
            }
        }
        __syncthreads();                                     // S6: VT visible
        // ---- ktv accumulate: C[m 32/wave][dl 128] over n = 64 ----
#pragma unroll
        for (int kk = 0; kk < 2; ++kk) {
            bf16x8 a[2];
#pragma unroll
            for (int i = 0; i < 2; ++i) {
                int row = wid * 32 + i * 16 + r16;
                a[i] = *(const bf16x8*)&KT[row * TL + swzc(row, kk * 32 + kgrp * 8)];
            }
#pragma unroll
            for (int j = 0; j < 8; ++j) {
                int row = j * 16 + r16;
                bf16x8 b = *(const bf16x8*)&VT[row * TL + swzc(row, kk * 32 + kgrp * 8)];
#pragma unroll
                for (int i = 0; i < 2; ++i)
                    kacc[i][j] = __builtin_amdgcn_mfma_f32_16x16x32_bf16(a[i], b, kacc[i][j], 0, 0, 0);
            }
        }
    }
    // ---- epilogue: private bf16 partial, fully line-coalesced ----
    {
        u16* Pb = P + (size_t)bid * 32768;                   // [dl 128][m 256] bf16 partial
#pragma unroll
        for (int i = 0; i < 2; ++i) {
#pragma unroll
            for (int j = 0; j < 8; ++j) {
                int dl = j * 16 + r16;
                int m0 = wid * 32 + i * 16 + kgrp * 4;
                ushort4 o;
                o.x = f2bf(kacc[i][j][0]); o.y = f2bf(kacc[i][j][1]);
                o.z = f2bf(kacc[i][j][2]); o.w = f2bf(kacc[i][j][3]);
                *(ushort4*)&Pb[dl * 256 + m0] = o;
            }
        }
    }
    if (dh == 0) atomicAdd(&ksum[h * 256 + (t >> 1)], ksr);
}

// ---------------- reduce partials: ktvb[h][dh*128+dl][m] = bf16( sum_g P[h,g,dh] ) ----------------
__global__ __launch_bounds__(256) void ktvreduce_kernel(const u16* __restrict__ P, u16* __restrict__ ktvb)
{
    int idx = blockIdx.x * 256 + threadIdx.x;    // 131072 ushort4 outputs
    int m4 = idx & 63, dl = (idx >> 6) & 127, dh = (idx >> 13) & 1, h = idx >> 14;
    float s0 = 0.f, s1 = 0.f, s2 = 0.f, s3 = 0.f;
#pragma unroll 4
    for (int g = 0; g < NG; ++g) {
        const u16* Pb = P + (size_t)(h + 8 * (g + NG * dh)) * 32768;
        ushort4 v = *(const ushort4*)&Pb[dl * 256 + m4 * 4];
        s0 += bf2f(v.x); s1 += bf2f(v.y); s2 += bf2f(v.z); s3 += bf2f(v.w);
    }
    ushort4 o;
    o.x = f2bf(s0); o.y = f2bf(s1); o.z = f2bf(s2); o.w = f2bf(s3);
    *(ushort4*)&ktvb[(size_t)h * 65536 + (size_t)(dh * 128 + dl) * 256 + m4 * 4] = o;
}

// ---------------- pass 3: q proj + phi + num/den + vss(avg) + mean + time ----------------
// 250 blocks x 80 rows (zero tail), 512 thr. Writes EVERY element of out (overwrites the
// P-scratch region that pass2 borrowed from d_out).
__global__ __launch_bounds__(512, 1) void pass3_kernel(
    const float* __restrict__ qf, const float* __restrict__ sf,
    const u16* __restrict__ Wqb, const float* __restrict__ bq,
    const float* __restrict__ ns_ptr, const u16* __restrict__ ktvb, const float* __restrict__ ksum,
    const u16* __restrict__ Wavg, const float* __restrict__ bavg, float* __restrict__ out)
{
    const int n0 = blockIdx.x * P3R;
    const int t = threadIdx.x;
    const int lane = t & 63, wid = t >> 6;      // 8 waves; wave = 80 rows x 32 cols
    const int r16 = lane & 15, kgrp = lane >> 4;
    const int C0 = wid * 32;

    __shared__ char smem[86016];
    u16* Xs = (u16*)smem;                        // [80][XS_LD] query tile 42240 B
    u16* Qs = (u16*)(smem + 42240);              // [80][XS_LD] phi_q (later source)
    float* ksl = (float*)(smem + 84480);         // 256 f32
    float* den = (float*)(smem + 85504);         // 80 f32
    float* outs = (float*)smem;                  // epilogue alias (80*256*4 = 81920 B)

    const float inv_ns = 1.0f / fabsf(ns_ptr[0]);

    // stage query tile (80 rows = 2560 int4, exact)
#pragma unroll
    for (int p = 0; p < 5; ++p) {
        int id = p * 512 + t;
        int row = id >> 5, col = (id & 31) * 8;
        *(int4*)&Xs[row * XS_LD + col] = cvt8(qf + ((size_t)(n0 + row) * 256 + col));
    }
    __syncthreads();

    f32x4 oacc[5][2];
#pragma unroll
    for (int f = 0; f < 5; ++f)
#pragma unroll
        for (int j = 0; j < 2; ++j) oacc[f][j] = (f32x4){0.f, 0.f, 0.f, 0.f};

    for (int h = 0; h < NH; ++h) {
        if (t < 256) ksl[t] = ksum[h * 256 + t];
        // ---- q-GEMM: C[n 80][m 256], wave cols C0..C0+31 ----
        f32x4 acc[5][2];
#pragma unroll
        for (int f = 0; f < 5; ++f)
#pragma unroll
            for (int j = 0; j < 2; ++j) acc[f][j] = (f32x4){0.f, 0.f, 0.f, 0.f};
#pragma unroll
        for (int kc = 0; kc < 4; ++kc) {
#pragma unroll
            for (int kk = 0; kk < 2; ++kk) {
                bf16x8 a[5], b[2];
#pragma unroll
                for (int f = 0; f < 5; ++f)
                    a[f] = *(const bf16x8*)&Xs[(f * 16 + r16) * XS_LD + kc * 64 + kk * 32 + kgrp * 8];
#pragma unroll
                for (int j = 0; j < 2; ++j)
                    b[j] = *(const bf16x8*)&Wqb[(size_t)h * 65536 +
                        (size_t)(C0 + j * 16 + r16) * 256 + kc * 64 + kk * 32 + kgrp * 8];
#pragma unroll
                for (int f = 0; f < 5; ++f)
#pragma unroll
                    for (int j = 0; j < 2; ++j)
                        acc[f][j] = __builtin_amdgcn_mfma_f32_16x16x32_bf16(a[f], b[j], acc[f][j], 0, 0, 0);
            }
        }
        __syncthreads();   // prev head's num reads of Qs done; ksl visible
        // epilogue: (relu+eps)*inv_ns -> Qs
#pragma unroll
        for (int f = 0; f < 5; ++f) {
#pragma unroll
            for (int j = 0; j < 2; ++j) {
                int c = C0 + j * 16 + r16;
#pragma unroll
                for (int r = 0; r < 4; ++r) {
                    int n = f * 16 + kgrp * 4 + r;
                    float x = acc[f][j][r] + bq[h * 256 + c];
                    x = (fmaxf(x, 0.f) + FEPS) * inv_ns;
                    Qs[n * XS_LD + c] = f2bf(x);
                }
            }
        }
        __syncthreads();
        // ---- phi row norms + apply + denominator (8 thr/row, 32 cols each) ----
#pragma unroll
        for (int rp = 0; rp < 2; ++rp) {
            int row = rp * 64 + (t >> 3);
            if (row < P3R) {
                int q = t & 7;
                float s1 = 0.f, s2 = 0.f;
                bf16x8 v8s[4];
#pragma unroll
                for (int j = 0; j < 4; ++j) {
                    v8s[j] = *(const bf16x8*)&Qs[row * XS_LD + q * 32 + j * 8];
#pragma unroll
                    for (int jj = 0; jj < 8; ++jj) {
                        float x = bf2f((u16)v8s[j][jj]);
                        float qq = x * x;
                        s1 += qq; s2 += qq * qq;
                    }
                }
                s1 += __shfl_xor(s1, 1, 64); s1 += __shfl_xor(s1, 2, 64); s1 += __shfl_xor(s1, 4, 64);
                s2 += __shfl_xor(s2, 1, 64); s2 += __shfl_xor(s2, 2, 64); s2 += __shfl_xor(s2, 4, 64);
                float sc = sqrtf(s1) / sqrtf(s2);
                float dp = 0.f;
#pragma unroll
                for (int j = 0; j < 4; ++j) {
                    bf16x8 w8;
#pragma unroll
                    for (int jj = 0; jj < 8; ++jj) {
                        float x = bf2f((u16)v8s[j][jj]);
                        float ph = x * x * sc;
                        u16 pb = f2bf(ph);
                        w8[jj] = (short)pb;
                        dp += bf2f(pb) * ksl[q * 32 + j * 8 + jj];
                    }
                    *(bf16x8*)&Qs[row * XS_LD + q * 32 + j * 8] = w8;
                }
                dp += __shfl_xor(dp, 1, 64); dp += __shfl_xor(dp, 2, 64); dp += __shfl_xor(dp, 4, 64);
                if (q == 0) den[row] = 0.125f / (dp + FEPS);   // mean folded
            }
        }
        __syncthreads();
        // ---- numerator GEMM: C[n][o] = phi_q x ktv[h] ----
#pragma unroll
        for (int f = 0; f < 5; ++f)
#pragma unroll
            for (int j = 0; j < 2; ++j) acc[f][j] = (f32x4){0.f, 0.f, 0.f, 0.f};
#pragma unroll
        for (int kc = 0; kc < 4; ++kc) {
#pragma unroll
            for (int kk = 0; kk < 2; ++kk) {
                bf16x8 a[5], b[2];
#pragma unroll
                for (int f = 0; f < 5; ++f)
                    a[f] = *(const bf16x8*)&Qs[(f * 16 + r16) * XS_LD + kc * 64 + kk * 32 + kgrp * 8];
#pragma unroll
                for (int j = 0; j < 2; ++j)
                    b[j] = *(const bf16x8*)&ktvb[(size_t)h * 65536 +
                        (size_t)(C0 + j * 16 + r16) * 256 + kc * 64 + kk * 32 + kgrp * 8];
#pragma unroll
                for (int f = 0; f < 5; ++f)
#pragma unroll
                    for (int j = 0; j < 2; ++j)
                        acc[f][j] = __builtin_amdgcn_mfma_f32_16x16x32_bf16(a[f], b[j], acc[f][j], 0, 0, 0);
            }
        }
#pragma unroll
        for (int f = 0; f < 5; ++f) {
#pragma unroll
            for (int r = 0; r < 4; ++r) {
                float dr = den[f * 16 + kgrp * 4 + r];
#pragma unroll
                for (int j = 0; j < 2; ++j)
                    oacc[f][j][r] += acc[f][j][r] * dr;
            }
        }
    }
    __syncthreads();
    // ---- stage source tile into Qs ----
#pragma unroll
    for (int p = 0; p < 5; ++p) {
        int id = p * 512 + t;
        int row = id >> 5, col = (id & 31) * 8;
        *(int4*)&Qs[row * XS_LD + col] = cvt8(sf + ((size_t)(n0 + row) * 256 + col));
    }
    __syncthreads();
    // ---- vss GEMM: C[n][o] = src x Wavg^T ----
    f32x4 vacc[5][2];
#pragma unroll
    for (int f = 0; f < 5; ++f)
#pragma unroll
        for (int j = 0; j < 2; ++j) vacc[f][j] = (f32x4){0.f, 0.f, 0.f, 0.f};
#pragma unroll
    for (int kc = 0; kc < 4; ++kc) {
#pragma unroll
        for (int kk = 0; kk < 2; ++kk) {
            bf16x8 a[5], b[2];
#pragma unroll
            for (int f = 0; f < 5; ++f)
                a[f] = *(const bf16x8*)&Qs[(f * 16 + r16) * XS_LD + kc * 64 + kk * 32 + kgrp * 8];
#pragma unroll
            for (int j = 0; j < 2; ++j)
                b[j] = *(const bf16x8*)&Wavg[(size_t)(C0 + j * 16 + r16) * 256 + kc * 64 + kk * 32 + kgrp * 8];
#pragma unroll
            for (int f = 0; f < 5; ++f)
#pragma unroll
                for (int j = 0; j < 2; ++j)
                    vacc[f][j] = __builtin_amdgcn_mfma_f32_16x16x32_bf16(a[f], b[j], vacc[f][j], 0, 0, 0);
        }
    }
    __syncthreads();   // tile reads done before outs alias writes
    // ---- combine into LDS ----
#pragma unroll
    for (int f = 0; f < 5; ++f) {
#pragma unroll
        for (int j = 0; j < 2; ++j) {
            int c = C0 + j * 16 + r16;
            float bo = bavg[c];
#pragma unroll
            for (int r = 0; r < 4; ++r) {
                int n = f * 16 + kgrp * 4 + r;
                outs[n * 256 + c] = oacc[f][j][r] + vacc[f][j][r] + bo;
            }
        }
    }
    __syncthreads();
    // ---- time component ----
#pragma unroll
    for (int rp = 0; rp < 2; ++rp) {
        int row = rp * 64 + (t >> 3);
        if (row < P3R) {
            int q = t & 7;
            float s = 0.f;
#pragma unroll
            for (int c4 = 0; c4 < 8; ++c4) {
                float4 v = *(const float4*)&outs[row * 256 + q * 32 + c4 * 4];
                s += v.x * v.x + v.y * v.y + v.z * v.z + v.w * v.w;
            }
            s += __shfl_xor(s, 1, 64); s += __shfl_xor(s, 2, 64); s += __shfl_xor(s, 4, 64);
            if (q == 0)
                out[(size_t)(n0 + row) * 257] = sqrtf(s + 1.0f);
        }
    }
    // ---- space components ----
    {
        int col = t & 255, half = t >> 8;
        for (int rr = 0; rr < 40; ++rr) {
            int row = half * 40 + rr;
            out[(size_t)(n0 + row) * 257 + 1 + col] = outs[row * 256 + col];
        }
    }
}

extern "C" void kernel_launch(void* const* d_in, const int* in_sizes, int n_in,
                              void* d_out, int out_size, void* d_ws, size_t ws_size,
                              hipStream_t stream)
{
    const float* query  = (const float*)d_in[0];
    const float* source = (const float*)d_in[1];
    const float* Wq_w   = (const float*)d_in[2];
    const float* Wq_b   = (const float*)d_in[3];
    const float* Wk_w   = (const float*)d_in[4];
    const float* Wk_b   = (const float*)d_in[5];
    const float* Wv_w   = (const float*)d_in[6];
    const float* Wv_b   = (const float*)d_in[7];
    const float* ns     = (const float*)d_in[8];
    const float* vmap_w = (const float*)d_in[9];
    const float* vmap_b = (const float*)d_in[10];
    float* out = (float*)d_out;

    char* ws = (char*)d_ws;
    size_t off = 0;
    auto alloc = [&](size_t bytes) -> char* {
        char* p = ws + off;
        off += (bytes + 255) & ~(size_t)255;
        return p;
    };
    // essentials (~4.4 MB; ws_size inferred ~6.4 MB from R2-R11 sentinel bracketing)
    float* ksum = (float*)alloc((size_t)NH * 256 * 4);
    u16*   Wqb  = (u16*)alloc((size_t)NH * 65536 * 2);
    u16*   Wkb  = (u16*)alloc((size_t)NH * 65536 * 2);
    u16*   Wvb  = (u16*)alloc((size_t)NH * 65536 * 2);
    float* Wsum = (float*)alloc((size_t)65536 * 4);
    u16*   Wavg = (u16*)alloc((size_t)65536 * 2);
    float* bavg = (float*)alloc((size_t)256 * 4);
    u16*   ktvb = (u16*)alloc((size_t)NH * 65536 * 2);

    if (off > ws_size) {
        hipMemsetAsync(d_out, 0x7f, (size_t)out_size * 4, stream);
        return;
    }

    // ktv partials live in d_out (16 MB of its 20.56 MB); pass3 overwrites all of
    // d_out afterwards, so this is replay-safe scratch with zero ws cost.
    u16* P = (u16*)d_out;

    hipMemsetAsync(ksum, 0, (size_t)NH * 256 * 4, stream);

    wprep_kernel<<<dim3(512, 4), 256, 0, stream>>>(Wq_w, Wk_w, Wv_w, Wqb, Wkb, Wvb, Wsum);
    wfin_kernel<<<257, 256, 0, stream>>>(Wsum, vmap_w, Wv_b, vmap_b, Wavg, bavg);

    pass2_kernel<<<16 * NG, 512, 0, stream>>>(source, Wkb, Wk_b, Wvb, Wv_b, ns, P, ksum);
    ktvreduce_kernel<<<512, 256, 0, stream>>>(P, ktvb);
    pass3_kernel<<<250, 512, 0, stream>>>(query, source, Wqb, Wq_b, ns, ktvb, ksum, Wavg, bavg, out);
}

// Round 21
// 314.356 us; speedup vs baseline: 1.0751x; 1.0751x over previous
//
#include <hip/hip_runtime.h>
#include <hip/hip_bf16.h>

#define N_NODES 20000
#define NH      8
#define NG      16      // node groups; 16*NG = 256 blocks (= 1 block/CU)
#define G2      1250    // nodes per group (16*1250 = 20000 exactly)
#define FEPS    1e-6f
#define XS_LD   264     // padded stride for [*][256] bf16 tiles (528B rows)
#define TL      72      // padded stride for [256][64]/[128][64] bf16 tiles (144B rows)
#define P3R     80      // pass-3 rows per block (250 * 80 = 20000 exactly)

typedef __attribute__((ext_vector_type(8))) short bf16x8;
typedef __attribute__((ext_vector_type(4))) float f32x4;
typedef unsigned short u16;

__device__ __forceinline__ float bf2f(u16 u) {
    union { unsigned int i; float f; } v; v.i = ((unsigned int)u) << 16; return v.f;
}
__device__ __forceinline__ u16 f2bf(float f) {
    union { float f; unsigned int i; } v; v.f = f;
    return (u16)((v.i + 0x7fffu + ((v.i >> 16) & 1u)) >> 16);
}
__device__ __forceinline__ int pk2(float a, float b) {
    return (int)f2bf(a) | ((int)f2bf(b) << 16);
}
__device__ __forceinline__ int4 cvt8(const float* __restrict__ s) {
    float4 a = *(const float4*)s;
    float4 b = *(const float4*)(s + 4);
    int4 w;
    w.x = pk2(a.x, a.y); w.y = pk2(a.z, a.w);
    w.z = pk2(b.x, b.y); w.w = pk2(b.z, b.w);
    return w;
}

// ---------------- fused prologue A: z<3 -> convert Wq/Wk/Wv; z==3 -> Wsum ----------------
__global__ __launch_bounds__(256) void wprep_kernel(
    const float* __restrict__ Wq, const float* __restrict__ Wk, const float* __restrict__ Wv,
    u16* __restrict__ Wqb, u16* __restrict__ Wkb, u16* __restrict__ Wvb,
    float* __restrict__ Wsum)
{
    const int z = blockIdx.y;
    if (z < 3) {
        const float* s = (z == 0) ? Wq : (z == 1) ? Wk : Wv;
        u16* d = (z == 0) ? Wqb : (z == 1) ? Wkb : Wvb;
        int i = blockIdx.x * 256 + threadIdx.x;    // 131072 float4s exactly
        float4 v = reinterpret_cast<const float4*>(s)[i];
        ushort4 o;
        o.x = f2bf(v.x); o.y = f2bf(v.y); o.z = f2bf(v.z); o.w = f2bf(v.w);
        reinterpret_cast<ushort4*>(d)[i] = o;
    } else {
        if (blockIdx.x >= 256) return;
        int i = blockIdx.x * 256 + threadIdx.x;    // 65536 elements
        float s = 0.f;
#pragma unroll
        for (int h = 0; h < NH; ++h) s += Wv[(size_t)h * 65536 + i];
        Wsum[i] = s;
    }
}

// ---------------- fused prologue B: o<256 -> Wavg row; o==256 -> bavg ----------------
__global__ __launch_bounds__(256) void wfin_kernel(
    const float* __restrict__ Wsum, const float* __restrict__ vmap_w,
    const float* __restrict__ bv, const float* __restrict__ vmap_b,
    u16* __restrict__ Wavg, float* __restrict__ bavg)
{
    const int o = blockIdx.x, t = threadIdx.x;
    __shared__ float buf[256];
    if (o < 256) {
        buf[t] = vmap_w[(size_t)o * 256 + t];
        __syncthreads();
        float acc = 0.f;
#pragma unroll 4
        for (int e = 0; e < 256; ++e)
            acc += buf[e] * Wsum[(size_t)e * 256 + t];
        Wavg[(size_t)o * 256 + t] = f2bf(acc * 0.125f);
    } else {
        float s = 0.f;
        for (int h = 0; h < NH; ++h) s += bv[h * 256 + t];
        buf[t] = s * 0.125f;
        __syncthreads();
        float acc = vmap_b[t];
        for (int e = 0; e < 256; ++e) acc += vmap_w[(size_t)t * 256 + e] * buf[e];
        bavg[t] = acc;
    }
}

// ---------------- pass 2: K/V proj + phi + ktv partial (256 blocks, 512 thr) ----------------
// bid -> h = bid&7 (XCD pin), g = (bid>>3)%NG, dh = (bid>>3)/NG.
// Partials go to P (= d_out used as scratch; pass3 fully overwrites d_out afterwards).
// NO ktv atomics (R5-R11: the fp32-atomic fallback cost 706 MB of coherence-point RMW).
// R13-R20 lessons (ALL falsified, each regressed 9-40%): reg-prefetch (L2 thrash),
// 2-block split, in-reg phi-norm, 16-wave blocks, 128-node tiles (spill), LDS
// chunk-swizzle (conflicts rose + VALU). This exact config measured 314.4 us x3.
__global__ __launch_bounds__(512, 2) void pass2_kernel(
    const float* __restrict__ srcf,
    const u16* __restrict__ Wkb, const float* __restrict__ bk,
    const u16* __restrict__ Wvb, const float* __restrict__ bv,
    const float* __restrict__ ns_ptr,
    u16* __restrict__ P,
    float* __restrict__ ksum)
{
    const int bid = blockIdx.x;
    const int h = bid & 7, gr = bid >> 3, g = gr % NG, dh = gr / NG;
    const int t = threadIdx.x;
    const int lane = t & 63, wid = t >> 6;      // 8 waves
    const int r16 = lane & 15, kgrp = lane >> 4;

    __shared__ char smem[75008];
    u16* Xs = (u16*)smem;                        // [64][XS_LD]  33792 B
    u16* VT = (u16*)smem;                        // [128][TL] 18432 B, OVERLAYS Xs
    u16* KT = (u16*)(smem + 33792);              // [256][TL]    36864 B
    float* red = (float*)(smem + 70656);         // 1024 f32
    float* scl = (float*)(smem + 74752);         // 64 f32

    const float inv_ns = 1.0f / fabsf(ns_ptr[0]);
    const u16* Wkh = Wkb + (size_t)h * 65536;
    const u16* Wvh = Wvb + (size_t)h * 65536;

    const int n0g = g * G2;
    const int rlim = min(G2, N_NODES - n0g);
    const int nt = (rlim + 63) >> 6;

    f32x4 kacc[2][8];
#pragma unroll
    for (int i = 0; i < 2; ++i)
#pragma unroll
        for (int j = 0; j < 8; ++j) kacc[i][j] = (f32x4){0.f, 0.f, 0.f, 0.f};
    float ksr = 0.f;

    for (int it = 0; it < nt; ++it) {
        const int ln0 = it * 64;
        __syncthreads();                                     // S0: prev iter VT reads done (overlay)
        // ---- stage X tile: fp32 -> bf16 in-register ----
#pragma unroll
        for (int p = 0; p < 4; ++p) {
            int id = p * 512 + t;
            int row = id >> 5, col = (id & 31) * 8;
            int4 w = {0, 0, 0, 0};
            if (ln0 + row < rlim)
                w = cvt8(srcf + ((size_t)(n0g + ln0 + row) * 256 + col));
            *(int4*)&Xs[row * XS_LD + col] = w;
        }
        __syncthreads();                                     // S1

        // ---- K-GEMM: C[m 256][n 64]; weights from L2 ----
        f32x4 acc2[2][4];
#pragma unroll
        for (int i = 0; i < 2; ++i)
#pragma unroll
            for (int j = 0; j < 4; ++j) acc2[i][j] = (f32x4){0.f, 0.f, 0.f, 0.f};
#pragma unroll
        for (int kc = 0; kc < 4; ++kc) {
#pragma unroll
            for (int kk = 0; kk < 2; ++kk) {
                bf16x8 a[2];
#pragma unroll
                for (int i = 0; i < 2; ++i)
                    a[i] = *(const bf16x8*)&Wkh[(size_t)(wid * 32 + i * 16 + r16) * 256 + kc * 64 + kk * 32 + kgrp * 8];
#pragma unroll
                for (int j = 0; j < 4; ++j) {
                    bf16x8 b = *(const bf16x8*)&Xs[(j * 16 + r16) * XS_LD + kc * 64 + kk * 32 + kgrp * 8];
#pragma unroll
                    for (int i = 0; i < 2; ++i)
                        acc2[i][j] = __builtin_amdgcn_mfma_f32_16x16x32_bf16(a[i], b, acc2[i][j], 0, 0, 0);
                }
            }
        }
        // epilogue -> KT: (relu + eps) * inv_ns
#pragma unroll
        for (int i = 0; i < 2; ++i) {
#pragma unroll
            for (int j = 0; j < 4; ++j) {
                int n = j * 16 + r16;
#pragma unroll
                for (int r = 0; r < 4; ++r) {
                    int m = wid * 32 + i * 16 + kgrp * 4 + r;
                    float x = acc2[i][j][r] + bk[h * 256 + m];
                    x = (fmaxf(x, 0.f) + FEPS) * inv_ns;
                    KT[m * TL + n] = f2bf(x);
                }
            }
        }
        __syncthreads();                                     // S2
        // ---- column reductions: per node c, s1=sum_m k'^2, s2=sum_m k'^4 ----
        {
            int c = t & 63, ch = t >> 6;
            float s1 = 0.f, s2 = 0.f;
#pragma unroll
            for (int i = 0; i < 32; ++i) {
                float x = bf2f(KT[(ch * 32 + i) * TL + c]);
                float q = x * x;
                s1 += q; s2 += q * q;
            }
            red[ch * 64 + c] = s1;
            red[512 + ch * 64 + c] = s2;
        }
        __syncthreads();                                     // S3
        if (t < 64) {
            float s1 = 0.f, s2 = 0.f;
#pragma unroll
            for (int ch = 0; ch < 8; ++ch) {
                s1 += red[ch * 64 + t];
                s2 += red[512 + ch * 64 + t];
            }
            scl[t] = (ln0 + t < rlim) ? sqrtf(s1) / sqrtf(s2) : 0.f;
        }
        __syncthreads();                                     // S4
        // ---- phi in place (row m = t>>1, n-half (t&1)*32) + ksum partial ----
        {
            const int m = t >> 1, q0 = (t & 1) * 32;
            float kp = 0.f;
#pragma unroll
            for (int j = 0; j < 4; ++j) {
                bf16x8 v8 = *(const bf16x8*)&KT[m * TL + q0 + j * 8];
                bf16x8 w8;
#pragma unroll
                for (int jj = 0; jj < 8; ++jj) {
                    float x = bf2f((u16)v8[jj]);
                    float ph = x * x * scl[q0 + j * 8 + jj];
                    u16 pb = f2bf(ph);
                    w8[jj] = (short)pb;
                    kp += bf2f(pb);
                }
                *(bf16x8*)&KT[m * TL + q0 + j * 8] = w8;
            }
            ksr += kp;
        }
        // ---- V-GEMM (d-half): C[dl 128][n 64]; all results in regs before overlay ----
        f32x4 accv[4];
#pragma unroll
        for (int j = 0; j < 4; ++j) accv[j] = (f32x4){0.f, 0.f, 0.f, 0.f};
#pragma unroll
        for (int kc = 0; kc < 4; ++kc) {
#pragma unroll
            for (int kk = 0; kk < 2; ++kk) {
                bf16x8 a = *(const bf16x8*)&Wvh[(size_t)(dh * 128 + wid * 16 + r16) * 256 + kc * 64 + kk * 32 + kgrp * 8];
#pragma unroll
                for (int j = 0; j < 4; ++j) {
                    bf16x8 b = *(const bf16x8*)&Xs[(j * 16 + r16) * XS_LD + kc * 64 + kk * 32 + kgrp * 8];
                    accv[j] = __builtin_amdgcn_mfma_f32_16x16x32_bf16(a, b, accv[j], 0, 0, 0);
                }
            }
        }
        __syncthreads();                                     // S5: all Xs reads done; phi'd KT visible
        // ---- write VT over Xs region ----
#pragma unroll
        for (int j = 0; j < 4; ++j) {
            int n = j * 16 + r16;
#pragma unroll
            for (int r = 0; r < 4; ++r) {
                int dl = wid * 16 + kgrp * 4 + r;
                VT[dl * TL + n] = f2bf(accv[j][r] + bv[h * 256 + dh * 128 + dl]);
            }
        }
        __syncthreads();                                     // S6: VT visible
        // ---- ktv accumulate: C[m 32/wave][dl 128] over n = 64 ----
#pragma unroll
        for (int kk = 0; kk < 2; ++kk) {
            bf16x8 a[2];
#pragma unroll
            for (int i = 0; i < 2; ++i)
                a[i] = *(const bf16x8*)&KT[(wid * 32 + i * 16 + r16) * TL + kk * 32 + kgrp * 8];
#pragma unroll
            for (int j = 0; j < 8; ++j) {
                bf16x8 b = *(const bf16x8*)&VT[(j * 16 + r16) * TL + kk * 32 + kgrp * 8];
#pragma unroll
                for (int i = 0; i < 2; ++i)
                    kacc[i][j] = __builtin_amdgcn_mfma_f32_16x16x32_bf16(a[i], b, kacc[i][j], 0, 0, 0);
            }
        }
    }
    // ---- epilogue: private bf16 partial, fully line-coalesced ----
    {
        u16* Pb = P + (size_t)bid * 32768;                   // [dl 128][m 256] bf16 partial
#pragma unroll
        for (int i = 0; i < 2; ++i) {
#pragma unroll
            for (int j = 0; j < 8; ++j) {
                int dl = j * 16 + r16;
                int m0 = wid * 32 + i * 16 + kgrp * 4;
                ushort4 o;
                o.x = f2bf(kacc[i][j][0]); o.y = f2bf(kacc[i][j][1]);
                o.z = f2bf(kacc[i][j][2]); o.w = f2bf(kacc[i][j][3]);
                *(ushort4*)&Pb[dl * 256 + m0] = o;
            }
        }
    }
    if (dh == 0) atomicAdd(&ksum[h * 256 + (t >> 1)], ksr);
}

// ---------------- reduce partials: ktvb[h][dh*128+dl][m] = bf16( sum_g P[h,g,dh] ) ----------------
__global__ __launch_bounds__(256) void ktvreduce_kernel(const u16* __restrict__ P, u16* __restrict__ ktvb)
{
    int idx = blockIdx.x * 256 + threadIdx.x;    // 131072 ushort4 outputs
    int m4 = idx & 63, dl = (idx >> 6) & 127, dh = (idx >> 13) & 1, h = idx >> 14;
    float s0 = 0.f, s1 = 0.f, s2 = 0.f, s3 = 0.f;
#pragma unroll 4
    for (int g = 0; g < NG; ++g) {
        const u16* Pb = P + (size_t)(h + 8 * (g + NG * dh)) * 32768;
        ushort4 v = *(const ushort4*)&Pb[dl * 256 + m4 * 4];
        s0 += bf2f(v.x); s1 += bf2f(v.y); s2 += bf2f(v.z); s3 += bf2f(v.w);
    }
    ushort4 o;
    o.x = f2bf(s0); o.y = f2bf(s1); o.z = f2bf(s2); o.w = f2bf(s3);
    *(ushort4*)&ktvb[(size_t)h * 65536 + (size_t)(dh * 128 + dl) * 256 + m4 * 4] = o;
}

// ---------------- pass 3: q proj + phi + num/den + vss(avg) + mean + time ----------------
// 250 blocks x 80 rows (zero tail), 512 thr. Writes EVERY element of out (overwrites the
// P-scratch region that pass2 borrowed from d_out).
__global__ __launch_bounds__(512, 1) void pass3_kernel(
    const float* __restrict__ qf, const float* __restrict__ sf,
    const u16* __restrict__ Wqb, const float* __restrict__ bq,
    const float* __restrict__ ns_ptr, const u16* __restrict__ ktvb, const float* __restrict__ ksum,
    const u16* __restrict__ Wavg, const float* __restrict__ bavg, float* __restrict__ out)
{
    const int n0 = blockIdx.x * P3R;
    const int t = threadIdx.x;
    const int lane = t & 63, wid = t >> 6;      // 8 waves; wave = 80 rows x 32 cols
    const int r16 = lane & 15, kgrp = lane >> 4;
    const int C0 = wid * 32;

    __shared__ char smem[86016];
    u16* Xs = (u16*)smem;                        // [80][XS_LD] query tile 42240 B
    u16* Qs = (u16*)(smem + 42240);              // [80][XS_LD] phi_q (later source)
    float* ksl = (float*)(smem + 84480);         // 256 f32
    float* den = (float*)(smem + 85504);         // 80 f32
    float* outs = (float*)smem;                  // epilogue alias (80*256*4 = 81920 B)

    const float inv_ns = 1.0f / fabsf(ns_ptr[0]);

    // stage query tile (80 rows = 2560 int4, exact)
#pragma unroll
    for (int p = 0; p < 5; ++p) {
        int id = p * 512 + t;
        int row = id >> 5, col = (id & 31) * 8;
        *(int4*)&Xs[row * XS_LD + col] = cvt8(qf + ((size_t)(n0 + row) * 256 + col));
    }
    __syncthreads();

    f32x4 oacc[5][2];
#pragma unroll
    for (int f = 0; f < 5; ++f)
#pragma unroll
        for (int j = 0; j < 2; ++j) oacc[f][j] = (f32x4){0.f, 0.f, 0.f, 0.f};

    for (int h = 0; h < NH; ++h) {
        if (t < 256) ksl[t] = ksum[h * 256 + t];
        // ---- q-GEMM: C[n 80][m 256], wave cols C0..C0+31 ----
        f32x4 acc[5][2];
#pragma unroll
        for (int f = 0; f < 5; ++f)
#pragma unroll
            for (int j = 0; j < 2; ++j) acc[f][j] = (f32x4){0.f, 0.f, 0.f, 0.f};
#pragma unroll
        for (int kc = 0; kc < 4; ++kc) {
#pragma unroll
            for (int kk = 0; kk < 2; ++kk) {
                bf16x8 a[5], b[2];
#pragma unroll
                for (int f = 0; f < 5; ++f)
                    a[f] = *(const bf16x8*)&Xs[(f * 16 + r16) * XS_LD + kc * 64 + kk * 32 + kgrp * 8];
#pragma unroll
                for (int j = 0; j < 2; ++j)
                    b[j] = *(const bf16x8*)&Wqb[(size_t)h * 65536 +
                        (size_t)(C0 + j * 16 + r16) * 256 + kc * 64 + kk * 32 + kgrp * 8];
#pragma unroll
                for (int f = 0; f < 5; ++f)
#pragma unroll
                    for (int j = 0; j < 2; ++j)
                        acc[f][j] = __builtin_amdgcn_mfma_f32_16x16x32_bf16(a[f], b[j], acc[f][j], 0, 0, 0);
            }
        }
        __syncthreads();   // prev head's num reads of Qs done; ksl visible
        // epilogue: (relu+eps)*inv_ns -> Qs
#pragma unroll
        for (int f = 0; f < 5; ++f) {
#pragma unroll
            for (int j = 0; j < 2; ++j) {
                int c = C0 + j * 16 + r16;
#pragma unroll
                for (int r = 0; r < 4; ++r) {
                    int n = f * 16 + kgrp * 4 + r;
                    float x = acc[f][j][r] + bq[h * 256 + c];
                    x = (fmaxf(x, 0.f) + FEPS) * inv_ns;
                    Qs[n * XS_LD + c] = f2bf(x);
                }
            }
        }
        __syncthreads();
        // ---- phi row norms + apply + denominator (8 thr/row, 32 cols each) ----
#pragma unroll
        for (int rp = 0; rp < 2; ++rp) {
            int row = rp * 64 + (t >> 3);
            if (row < P3R) {
                int q = t & 7;
                float s1 = 0.f, s2 = 0.f;
                bf16x8 v8s[4];
#pragma unroll
                for (int j = 0; j < 4; ++j) {
                    v8s[j] = *(const bf16x8*)&Qs[row * XS_LD + q * 32 + j * 8];
#pragma unroll
                    for (int jj = 0; jj < 8; ++jj) {
                        float x = bf2f((u16)v8s[j][jj]);
                        float qq = x * x;
                        s1 += qq; s2 += qq * qq;
                    }
                }
                s1 += __shfl_xor(s1, 1, 64); s1 += __shfl_xor(s1, 2, 64); s1 += __shfl_xor(s1, 4, 64);
                s2 += __shfl_xor(s2, 1, 64); s2 += __shfl_xor(s2, 2, 64); s2 += __shfl_xor(s2, 4, 64);
                float sc = sqrtf(s1) / sqrtf(s2);
                float dp = 0.f;
#pragma unroll
                for (int j = 0; j < 4; ++j) {
                    bf16x8 w8;
#pragma unroll
                    for (int jj = 0; jj < 8; ++jj) {
                        float x = bf2f((u16)v8s[j][jj]);
                        float ph = x * x * sc;
                        u16 pb = f2bf(ph);
                        w8[jj] = (short)pb;
                        dp += bf2f(pb) * ksl[q * 32 + j * 8 + jj];
                    }
                    *(bf16x8*)&Qs[row * XS_LD + q * 32 + j * 8] = w8;
                }
                dp += __shfl_xor(dp, 1, 64); dp += __shfl_xor(dp, 2, 64); dp += __shfl_xor(dp, 4, 64);
                if (q == 0) den[row] = 0.125f / (dp + FEPS);   // mean folded
            }
        }
        __syncthreads();
        // ---- numerator GEMM: C[n][o] = phi_q x ktv[h] ----
#pragma unroll
        for (int f = 0; f < 5; ++f)
#pragma unroll
            for (int j = 0; j < 2; ++j) acc[f][j] = (f32x4){0.f, 0.f, 0.f, 0.f};
#pragma unroll
        for (int kc = 0; kc < 4; ++kc) {
#pragma unroll
            for (int kk = 0; kk < 2; ++kk) {
                bf16x8 a[5], b[2];
#pragma unroll
                for (int f = 0; f < 5; ++f)
                    a[f] = *(const bf16x8*)&Qs[(f * 16 + r16) * XS_LD + kc * 64 + kk * 32 + kgrp * 8];
#pragma unroll
                for (int j = 0; j < 2; ++j)
                    b[j] = *(const bf16x8*)&ktvb[(size_t)h * 65536 +
                        (size_t)(C0 + j * 16 + r16) * 256 + kc * 64 + kk * 32 + kgrp * 8];
#pragma unroll
                for (int f = 0; f < 5; ++f)
#pragma unroll
                    for (int j = 0; j < 2; ++j)
                        acc[f][j] = __builtin_amdgcn_mfma_f32_16x16x32_bf16(a[f], b[j], acc[f][j], 0, 0, 0);
            }
        }
#pragma unroll
        for (int f = 0; f < 5; ++f) {
#pragma unroll
            for (int r = 0; r < 4; ++r) {
                float dr = den[f * 16 + kgrp * 4 + r];
#pragma unroll
                for (int j = 0; j < 2; ++j)
                    oacc[f][j][r] += acc[f][j][r] * dr;
            }
        }
    }
    __syncthreads();
    // ---- stage source tile into Qs ----
#pragma unroll
    for (int p = 0; p < 5; ++p) {
        int id = p * 512 + t;
        int row = id >> 5, col = (id & 31) * 8;
        *(int4*)&Qs[row * XS_LD + col] = cvt8(sf + ((size_t)(n0 + row) * 256 + col));
    }
    __syncthreads();
    // ---- vss GEMM: C[n][o] = src x Wavg^T ----
    f32x4 vacc[5][2];
#pragma unroll
    for (int f = 0; f < 5; ++f)
#pragma unroll
        for (int j = 0; j < 2; ++j) vacc[f][j] = (f32x4){0.f, 0.f, 0.f, 0.f};
#pragma unroll
    for (int kc = 0; kc < 4; ++kc) {
#pragma unroll
        for (int kk = 0; kk < 2; ++kk) {
            bf16x8 a[5], b[2];
#pragma unroll
            for (int f = 0; f < 5; ++f)
                a[f] = *(const bf16x8*)&Qs[(f * 16 + r16) * XS_LD + kc * 64 + kk * 32 + kgrp * 8];
#pragma unroll
            for (int j = 0; j < 2; ++j)
                b[j] = *(const bf16x8*)&Wavg[(size_t)(C0 + j * 16 + r16) * 256 + kc * 64 + kk * 32 + kgrp * 8];
#pragma unroll
            for (int f = 0; f < 5; ++f)
#pragma unroll
                for (int j = 0; j < 2; ++j)
                    vacc[f][j] = __builtin_amdgcn_mfma_f32_16x16x32_bf16(a[f], b[j], vacc[f][j], 0, 0, 0);
        }
    }
    __syncthreads();   // tile reads done before outs alias writes
    // ---- combine into LDS ----
#pragma unroll
    for (int f = 0; f < 5; ++f) {
#pragma unroll
        for (int j = 0; j < 2; ++j) {
            int c = C0 + j * 16 + r16;
            float bo = bavg[c];
#pragma unroll
            for (int r = 0; r < 4; ++r) {
                int n = f * 16 + kgrp * 4 + r;
                outs[n * 256 + c] = oacc[f][j][r] + vacc[f][j][r] + bo;
            }
        }
    }
    __syncthreads();
    // ---- time component ----
#pragma unroll
    for (int rp = 0; rp < 2; ++rp) {
        int row = rp * 64 + (t >> 3);
        if (row < P3R) {
            int q = t & 7;
            float s = 0.f;
#pragma unroll
            for (int c4 = 0; c4 < 8; ++c4) {
                float4 v = *(const float4*)&outs[row * 256 + q * 32 + c4 * 4];
                s += v.x * v.x + v.y * v.y + v.z * v.z + v.w * v.w;
            }
            s += __shfl_xor(s, 1, 64); s += __shfl_xor(s, 2, 64); s += __shfl_xor(s, 4, 64);
            if (q == 0)
                out[(size_t)(n0 + row) * 257] = sqrtf(s + 1.0f);
        }
    }
    // ---- space components ----
    {
        int col = t & 255, half = t >> 8;
        for (int rr = 0; rr < 40; ++rr) {
            int row = half * 40 + rr;
            out[(size_t)(n0 + row) * 257 + 1 + col] = outs[row * 256 + col];
        }
    }
}

extern "C" void kernel_launch(void* const* d_in, const int* in_sizes, int n_in,
                              void* d_out, int out_size, void* d_ws, size_t ws_size,
                              hipStream_t stream)
{
    const float* query  = (const float*)d_in[0];
    const float* source = (const float*)d_in[1];
    const float* Wq_w   = (const float*)d_in[2];
    const float* Wq_b   = (const float*)d_in[3];
    const float* Wk_w   = (const float*)d_in[4];
    const float* Wk_b   = (const float*)d_in[5];
    const float* Wv_w   = (const float*)d_in[6];
    const float* Wv_b   = (const float*)d_in[7];
    const float* ns     = (const float*)d_in[8];
    const float* vmap_w = (const float*)d_in[9];
    const float* vmap_b = (const float*)d_in[10];
    float* out = (float*)d_out;

    char* ws = (char*)d_ws;
    size_t off = 0;
    auto alloc = [&](size_t bytes) -> char* {
        char* p = ws + off;
        off += (bytes + 255) & ~(size_t)255;
        return p;
    };
    // essentials (~4.4 MB; ws_size inferred ~6.4 MB from R2-R11 sentinel bracketing)
    float* ksum = (float*)alloc((size_t)NH * 256 * 4);
    u16*   Wqb  = (u16*)alloc((size_t)NH * 65536 * 2);
    u16*   Wkb  = (u16*)alloc((size_t)NH * 65536 * 2);
    u16*   Wvb  = (u16*)alloc((size_t)NH * 65536 * 2);
    float* Wsum = (float*)alloc((size_t)65536 * 4);
    u16*   Wavg = (u16*)alloc((size_t)65536 * 2);
    float* bavg = (float*)alloc((size_t)256 * 4);
    u16*   ktvb = (u16*)alloc((size_t)NH * 65536 * 2);

    if (off > ws_size) {
        hipMemsetAsync(d_out, 0x7f, (size_t)out_size * 4, stream);
        return;
    }

    // ktv partials live in d_out (16 MB of its 20.56 MB); pass3 overwrites all of
    // d_out afterwards, so this is replay-safe scratch with zero ws cost.
    u16* P = (u16*)d_out;

    hipMemsetAsync(ksum, 0, (size_t)NH * 256 * 4, stream);

    wprep_kernel<<<dim3(512, 4), 256, 0, stream>>>(Wq_w, Wk_w, Wv_w, Wqb, Wkb, Wvb, Wsum);
    wfin_kernel<<<257, 256, 0, stream>>>(Wsum, vmap_w, Wv_b, vmap_b, Wavg, bavg);

    pass2_kernel<<<16 * NG, 512, 0, stream>>>(source, Wkb, Wk_b, Wvb, Wv_b, ns, P, ksum);
    ktvreduce_kernel<<<512, 256, 0, stream>>>(P, ktvb);
    pass3_kernel<<<250, 512, 0, stream>>>(query, source, Wqb, Wq_b, ns, ktvb, ksum, Wavg, bavg, out);
}